// Round 4
// baseline (2958.028 us; speedup 1.0000x reference)
//
#include <hip/hip_runtime.h>
#include <stdint.h>

// Problem constants (B,F,S,H) = (256, 2, 256, 128)
#define BB 256
#define SS 256
#define HH 128
#define NT 512
#define CHUNK 8
#define GLD 132   // G_T row stride in floats: 33 x 16B granules, 33 % 32 == 1
                  // -> natural bank-group rotation, conflict-free float4 access
#define NEG_INF (-3.402823466e+38f)

// JAX >= 0.4.30 defaults jax_threefry_partitionable=True. If correctness fails
// with wholesale trajectory divergence, set this to 0 (legacy split-counter).
#define JAX_PARTITIONABLE 1
// Harness doc says non-bf16 outputs are float*; set to 1 if tours segment
// must instead be raw int32 bits.
#define TOURS_AS_INT 0

// ---------------- threefry-2x32 (exact JAX rotation/injection schedule) -----
__device__ __forceinline__ void tf2x32(unsigned int k0, unsigned int k1,
                                       unsigned int x0, unsigned int x1,
                                       unsigned int& o0, unsigned int& o1) {
  unsigned int k2 = k0 ^ k1 ^ 0x1BD11BDAu;
  x0 += k0; x1 += k1;
#define TFR(r) { x0 += x1; x1 = (x1 << (r)) | (x1 >> (32 - (r))); x1 ^= x0; }
  TFR(13) TFR(15) TFR(26) TFR(6)
  x0 += k1; x1 += k2 + 1u;
  TFR(17) TFR(29) TFR(16) TFR(24)
  x0 += k2; x1 += k0 + 2u;
  TFR(13) TFR(15) TFR(26) TFR(6)
  x0 += k0; x1 += k1 + 3u;
  TFR(17) TFR(29) TFR(16) TFR(24)
  x0 += k1; x1 += k2 + 4u;
  TFR(13) TFR(15) TFR(26) TFR(6)
  x0 += k2; x1 += k0 + 5u;
#undef TFR
  o0 = x0; o1 = x1;
}

// uniform(minval=tiny, maxval=1) -> gumbel, exactly as jax.random.gumbel
__device__ __forceinline__ float gumbel_from_bits(unsigned int bits) {
  unsigned int fb = (bits >> 9) | 0x3f800000u;
  float f = __uint_as_float(fb) - 1.0f;   // [0,1)
  f = (f == 0.0f) ? 1.17549435e-38f : f;  // *(1-tiny)+tiny == f except f==0
  return -logf(-logf(f));
}

// ---------------- XLA EmitTanh (clamp +-9, Eigen rational), unfused ---------
__device__ __forceinline__ float xla_tanh(float x) {
  float ax = fabsf(x);
  float xc = fminf(fmaxf(x, -9.0f), 9.0f);
  float x2 = __fmul_rn(xc, xc);
  float p = -2.76076847742355e-16f;
  p = __fadd_rn(__fmul_rn(x2, p),  2.00018790482477e-13f);
  p = __fadd_rn(__fmul_rn(x2, p), -8.60467152213735e-11f);
  p = __fadd_rn(__fmul_rn(x2, p),  5.12229709037114e-08f);
  p = __fadd_rn(__fmul_rn(x2, p),  1.48572235717979e-05f);
  p = __fadd_rn(__fmul_rn(x2, p),  6.37261928875436e-04f);
  p = __fadd_rn(__fmul_rn(x2, p),  4.89352455891786e-03f);
  p = __fmul_rn(xc, p);
  float q = 1.19825839466702e-06f;
  q = __fadd_rn(__fmul_rn(x2, q), 1.18534705686654e-04f);
  q = __fadd_rn(__fmul_rn(x2, q), 2.26843463243900e-03f);
  q = __fadd_rn(__fmul_rn(x2, q), 4.89352518554385e-03f);
  float r = __fdiv_rn(p, q);
  return (ax < 0.0004f) ? x : r;
}

// XLA LogisticExpander: sigmoid(x) = 0.5 + 0.5*tanh(0.5*x)
__device__ __forceinline__ float xla_sigmoid(float x) {
  return __fadd_rn(0.5f, __fmul_rn(0.5f, xla_tanh(__fmul_rn(0.5f, x))));
}

// ---------------- weight transposes into ws (coalesce per-step reads) -------
// ws layout (floats): WdecT[128][128] @0 | WihT[128][512] @16384 |
//                     WhhT[128][512] @81920 | Wa3T[128][128] @147456
__global__ void transpose_weights(const float* __restrict__ Wdec,
                                  const float* __restrict__ Wih,
                                  const float* __restrict__ Whh,
                                  const float* __restrict__ Wa,
                                  float* __restrict__ ws) {
  int i = blockIdx.x * blockDim.x + threadIdx.x;
  if (i < 16384) {
    int k = i >> 7, j = i & 127;
    ws[i] = Wdec[j * 128 + k];
  } else if (i < 16384 + 65536) {
    int r = i - 16384; int k = r >> 9, g = r & 511;
    ws[16384 + r] = Wih[g * 128 + k];
  } else if (i < 16384 + 131072) {
    int r = i - 81920; int k = r >> 9, g = r & 511;
    ws[81920 + r] = Whh[g * 128 + k];
  } else if (i < 16384 + 131072 + 16384) {
    int r = i - 147456; int k = r >> 7, h = r & 127;
    ws[147456 + r] = Wa[h * 384 + 256 + k];
  }
}

// ---------------- persistent per-batch mega-kernel --------------------------
__global__ __launch_bounds__(NT, 2)
void ptrnet_megakernel(const float* __restrict__ SE,     // (B,H,S)
                       const float* __restrict__ dyn,    // (B,F,S)
                       const float* __restrict__ Wdyn,   // (H,F)
                       const float* __restrict__ bdyn,   // (H)
                       const float* __restrict__ Wa,     // (H,3H)
                       const float* __restrict__ v_att,  // (H)
                       const float* __restrict__ bdec_g, // (H)
                       const float* __restrict__ bih,    // (4H)
                       const float* __restrict__ bhh,    // (4H)
                       const float* __restrict__ ws,     // transposed weights
                       float* __restrict__ out)          // tours(B,S)|logps(B,S)
{
  const int b    = blockIdx.x;
  const int tid  = threadIdx.x;
  const int j8   = tid & 255;   // column-list position (E/F/G phases)
  const int half = tid >> 8;    // h-half for E
  const int jd   = tid & 127;   // output index, partitioned GEMVs
  const int pd   = tid >> 7;    // k-partition 0..3, partitioned GEMVs

  const float* WdecT = ws;            // [k][j]
  const float* WihT  = ws + 16384;    // [k][g]
  const float* WhhT  = ws + 81920;    // [k][g]
  const float* Wa3T  = ws + 147456;   // [k][h]

  // s-major attention base: row stride 132 floats (33x16B, rotation-1 banks)
  __shared__ __align__(16) float G_T[SS * GLD];       // 132 KiB
  __shared__ __align__(16) float gxbuf[CHUNK][NT];    // 16 KiB
  __shared__ __align__(16) float xbuf[CHUNK + 1][HH]; // 4.5 KiB (row 0 = carry)
  __shared__ __align__(16) float gate[NT];            // GEMV/reduce scratch
  __shared__ __align__(16) float hS[HH], cS[HH], w3h[HH], vS[HH], bdecS[HH];
  __shared__ float sc[SS], kv[SS];
  __shared__ float red[32];
  __shared__ unsigned char alist[SS];
  __shared__ int nactS;

  // ---- Precompute G_T[s][h] = (Wa1@SE + (Wa2@Wdyn)@dyn0 + Wa2@bdyn)[h,s] ----
  {
    float* Msh  = &xbuf[0][0];   // 256 floats scratch (rows 0-1)
    float* c2   = &xbuf[2][0];   // 128 floats scratch
    float* SEst = &gxbuf[0][0];  // 2048 floats scratch (rows 0-3)
    if (tid < 256) {
      int h = tid >> 1, f = tid & 1;
      float a = 0.f;
      for (int k = 0; k < HH; ++k)
        a = fmaf(Wa[h * 384 + 128 + k], Wdyn[k * 2 + f], a);
      Msh[tid] = a;
    } else if (tid < 384) {
      int h = tid - 256;
      float a = 0.f;
      for (int k = 0; k < HH; ++k)
        a = fmaf(Wa[h * 384 + 128 + k], bdyn[k], a);
      c2[h] = a;
    }
    __syncthreads();
    {
      float d0 = dyn[(size_t)(b * 2 + 0) * SS + j8];
      float d1 = dyn[(size_t)(b * 2 + 1) * SS + j8];
      const int h0 = half << 6;
      #pragma unroll 4
      for (int i4 = 0; i4 < 16; ++i4) {
        int h = h0 + i4 * 4;
        float4 g;
        g.x = c2[h + 0] + Msh[(h + 0) * 2] * d0 + Msh[(h + 0) * 2 + 1] * d1;
        g.y = c2[h + 1] + Msh[(h + 1) * 2] * d0 + Msh[(h + 1) * 2 + 1] * d1;
        g.z = c2[h + 2] + Msh[(h + 2) * 2] * d0 + Msh[(h + 2) * 2 + 1] * d1;
        g.w = c2[h + 3] + Msh[(h + 3) * 2] * d0 + Msh[(h + 3) * 2 + 1] * d1;
        *(float4*)&G_T[j8 * GLD + h] = g;
      }
    }
    __syncthreads();
    for (int kt = 0; kt < 16; ++kt) {   // k-tiles of 8
      #pragma unroll
      for (int r = 0; r < 4; ++r) {
        int idx = r * 512 + tid;
        int kk = idx >> 8, ssx = idx & 255;
        SEst[kk * 256 + ssx] = SE[(size_t)(b * HH + kt * 8 + kk) * SS + ssx];
      }
      __syncthreads();
      float se[8];
      #pragma unroll
      for (int j = 0; j < 8; ++j) se[j] = SEst[j * 256 + j8];
      const int h0 = half << 6;
      for (int i4 = 0; i4 < 16; ++i4) {
        int h = h0 + i4 * 4;
        float4 g = *(const float4*)&G_T[j8 * GLD + h];
        #pragma unroll
        for (int c = 0; c < 4; ++c) {
          const float* war = Wa + (h + c) * 384 + kt * 8;
          float a = 0.f;
          #pragma unroll
          for (int j = 0; j < 8; ++j) a = fmaf(war[j], se[j], a);
          ((float*)&g)[c] += a;
        }
        *(float4*)&G_T[j8 * GLD + h] = g;
      }
      __syncthreads();
    }
  }

  // ---- init rollout state ----
  if (tid < HH) {
    hS[tid] = 0.f; cS[tid] = 0.f;
    xbuf[0][tid] = SE[(size_t)(b * HH + tid) * SS];  // dec_in0 = SE[:,:,0]
    bdecS[tid] = bdec_g[tid];
    vS[tid]    = v_att[tid];
  }
  if (tid < 256) alist[tid] = (unsigned char)tid;
  if (tid == 0) nactS = 256;

  // ---- pin long-lived weight slices in VGPRs ----
  float whh_r[HH];                       // full Whh row for gate `tid`
  #pragma unroll
  for (int k = 0; k < HH; ++k) whh_r[k] = WhhT[k * 512 + tid];
  float wdec_r[32];                      // Wdec col jd, k in [32*pd, 32*pd+32)
  #pragma unroll
  for (int kk = 0; kk < 32; ++kk) wdec_r[kk] = WdecT[(pd * 32 + kk) * HH + jd];
  float wa3_r[32];                       // Wa3 col jd, same k-slice
  #pragma unroll
  for (int kk = 0; kk < 32; ++kk) wa3_r[kk] = Wa3T[(pd * 32 + kk) * HH + jd];
  __syncthreads();

  // ---- 256 sequential decode steps ----
  for (int t = 0; t < SS; ++t) {
    const int i = t & (CHUNK - 1);

    if (i == 0) {
      // ---- chunk prologue: advance x-chain 8 steps (partitioned GEMV) ----
      for (int ii = 0; ii < CHUNK; ++ii) {
        float a = 0.f;
        #pragma unroll
        for (int kk = 0; kk < 32; ++kk)
          a = fmaf(xbuf[ii][pd * 32 + kk], wdec_r[kk], a);
        gate[pd * 128 + jd] = a;
        __syncthreads();
        if (tid < HH) {
          float sum = ((gate[tid] + gate[128 + tid]) + gate[256 + tid]) + gate[384 + tid];
          xbuf[ii + 1][tid] = __fadd_rn(sum, bdecS[tid]);
        }
        __syncthreads();
      }
      if (tid < HH) xbuf[0][tid] = xbuf[CHUNK][tid];  // carry for next chunk
      // ---- batch gate-inputs: gx = Wih@x + (bih+bhh), Wih streamed 2x ----
      float bihhh = bih[tid] + bhh[tid];
      #pragma unroll
      for (int pass = 0; pass < 2; ++pass) {
        const float* xA = &xbuf[pass * 4 + 1][0];
        const float* xB = &xbuf[pass * 4 + 2][0];
        const float* xC = &xbuf[pass * 4 + 3][0];
        const float* xD = &xbuf[pass * 4 + 4][0];
        float a0 = bihhh, a1 = bihhh, a2 = bihhh, a3 = bihhh;
        #pragma unroll 8
        for (int k4 = 0; k4 < 32; ++k4) {
          float w0 = WihT[(k4 * 4 + 0) * 512 + tid];
          float w1 = WihT[(k4 * 4 + 1) * 512 + tid];
          float w2 = WihT[(k4 * 4 + 2) * 512 + tid];
          float w3 = WihT[(k4 * 4 + 3) * 512 + tid];
          float4 va = *(const float4*)&xA[k4 * 4];
          float4 vb = *(const float4*)&xB[k4 * 4];
          float4 vc = *(const float4*)&xC[k4 * 4];
          float4 vd = *(const float4*)&xD[k4 * 4];
          a0 = fmaf(va.x, w0, a0); a0 = fmaf(va.y, w1, a0);
          a0 = fmaf(va.z, w2, a0); a0 = fmaf(va.w, w3, a0);
          a1 = fmaf(vb.x, w0, a1); a1 = fmaf(vb.y, w1, a1);
          a1 = fmaf(vb.z, w2, a1); a1 = fmaf(vb.w, w3, a1);
          a2 = fmaf(vc.x, w0, a2); a2 = fmaf(vc.y, w1, a2);
          a2 = fmaf(vc.z, w2, a2); a2 = fmaf(vc.w, w3, a2);
          a3 = fmaf(vd.x, w0, a3); a3 = fmaf(vd.y, w1, a3);
          a3 = fmaf(vd.z, w2, a3); a3 = fmaf(vd.w, w3, a3);
        }
        gxbuf[pass * 4 + 0][tid] = a0;
        gxbuf[pass * 4 + 1][tid] = a1;
        gxbuf[pass * 4 + 2][tid] = a2;
        gxbuf[pass * 4 + 3][tid] = a3;
      }
      __syncthreads();
    }

    // A: gates = gx + h @ Whh^T  (k-ascending, Whh row in VGPRs)
    {
      float g = gxbuf[i][tid];
      #pragma unroll
      for (int k4 = 0; k4 < HH / 4; ++k4) {
        float4 hv = *(const float4*)&hS[k4 * 4];
        g = fmaf(hv.x, whh_r[k4 * 4 + 0], g);
        g = fmaf(hv.y, whh_r[k4 * 4 + 1], g);
        g = fmaf(hv.z, whh_r[k4 * 4 + 2], g);
        g = fmaf(hv.w, whh_r[k4 * 4 + 3], g);
      }
      gate[tid] = g;
    }
    __syncthreads();
    // C: LSTM cell
    if (tid < HH) {
      float gi = gate[tid], gf = gate[128 + tid];
      float gg = gate[256 + tid], go = gate[384 + tid];
      float c_new = __fadd_rn(__fmul_rn(xla_sigmoid(gf), cS[tid]),
                              __fmul_rn(xla_sigmoid(gi), xla_tanh(gg)));
      float h_new = __fmul_rn(xla_sigmoid(go), xla_tanh(c_new));
      cS[tid] = c_new; hS[tid] = h_new;
    }
    __syncthreads();

    if (t == 0) {
      // Only s=0 allowed at t=0: ptr=0 guaranteed, logp = 0 exactly
      // (single-finite-logit log_softmax). Skip D/E/F/G entirely.
      if (tid == 0) {
#if TOURS_AS_INT
        ((int*)out)[b * SS + 0] = 0;
#else
        out[b * SS + 0] = 0.0f;
#endif
        out[BB * SS + b * SS + 0] = 0.0f;
        alist[0] = alist[255];   // swap-remove s=0 (at list position 0)
        nactS = 255;
      }
      continue;  // next step's barriers order these writes before any read
    }

    // D: w3h = Wa3 @ h  (partitioned 4x32, Wa3 slice in VGPRs)
    {
      float a = 0.f;
      #pragma unroll
      for (int kk = 0; kk < 32; ++kk)
        a = fmaf(hS[pd * 32 + kk], wa3_r[kk], a);
      gate[pd * 128 + jd] = a;   // gate[] dead here; reuse as reduce scratch
    }
    __syncthreads();
    if (tid < HH)
      w3h[tid] = ((gate[tid] + gate[128 + tid]) + gate[256 + tid]) + gate[384 + tid];
    __syncthreads();

    const int nact = nactS;

    // E: partial scores over active columns only (float4 G_T reads,
    // bank-rotation-free layout; h-ascending accumulation per half)
    if (j8 < nact) {
      const int s = alist[j8];
      const float* grow = &G_T[s * GLD];
      float acc = 0.f;
      const int h0 = half << 6;
      #pragma unroll 4
      for (int i4 = 0; i4 < 16; ++i4) {
        int h = h0 + i4 * 4;
        float4 gv = *(const float4*)&grow[h];
        float4 wv = *(const float4*)&w3h[h];
        float4 vv = *(const float4*)&vS[h];
        float z0 = __fadd_rn(gv.x, wv.x);
        float z1 = __fadd_rn(gv.y, wv.y);
        float z2 = __fadd_rn(gv.z, wv.z);
        float z3 = __fadd_rn(gv.w, wv.w);
        acc = fmaf(vv.x, xla_tanh(z0), acc);
        acc = fmaf(vv.y, xla_tanh(z1), acc);
        acc = fmaf(vv.z, xla_tanh(z2), acc);
        acc = fmaf(vv.w, xla_tanh(z3), acc);
      }
      if (half == 0) sc[j8] = acc; else kv[j8] = acc;
    }
    __syncthreads();

    // F+G1: logits + gumbel keys, then argmax (tie-break: lowest s) and max
    if (tid < 256) {
      float val, mx; int sidx, jpos;
      if (j8 < nact) {
        const int s = alist[j8];
        float logit = __fadd_rn(sc[j8], kv[j8]);
        unsigned int fk0, fk1, o0, o1, bits;
        tf2x32(0u, 42u, 0u, (unsigned int)t, fk0, fk1);  // fold_in(key(42), t)
#if JAX_PARTITIONABLE
        tf2x32(fk0, fk1, 0u, (unsigned int)(b * 256 + s), o0, o1);
        bits = o0 ^ o1;
#else
        int jj = b * 256 + s;
        if (jj < 32768) { tf2x32(fk0, fk1, (unsigned)jj, (unsigned)(jj + 32768), o0, o1); bits = o0; }
        else            { tf2x32(fk0, fk1, (unsigned)(jj - 32768), (unsigned)jj, o0, o1); bits = o1; }
#endif
        float gum = gumbel_from_bits(bits);
        val = __fadd_rn(logit, gum);
        sc[j8] = logit;           // keep logit for G2/H
        mx = logit; sidx = s; jpos = j8;
      } else {
        val = -INFINITY; mx = -INFINITY; sidx = 0x7FFFFFFF; jpos = 0;
      }
      #pragma unroll
      for (int off = 1; off < 64; off <<= 1) {
        float ov = __shfl_xor(val, off);
        int   oi = __shfl_xor(sidx, off);
        int   oj = __shfl_xor(jpos, off);
        float om = __shfl_xor(mx, off);
        if (ov > val || (ov == val && oi < sidx)) { val = ov; sidx = oi; jpos = oj; }
        mx = fmaxf(mx, om);
      }
      if ((tid & 63) == 0) {
        int w = tid >> 6;
        red[w * 4 + 0] = val;
        red[w * 4 + 1] = __int_as_float(sidx);
        red[w * 4 + 2] = __int_as_float(jpos);
        red[w * 4 + 3] = mx;
      }
    }
    __syncthreads();
    if (tid == 0) {
      float bv = red[0]; int bs = __float_as_int(red[1]);
      int bj = __float_as_int(red[2]); float bm = red[3];
      #pragma unroll
      for (int w = 1; w < 4; ++w) {
        float ov = red[w * 4], om = red[w * 4 + 3];
        int os = __float_as_int(red[w * 4 + 1]);
        int oj = __float_as_int(red[w * 4 + 2]);
        if (ov > bv || (ov == bv && os < bs)) { bv = ov; bs = os; bj = oj; }
        bm = fmaxf(bm, om);
      }
      red[16] = __int_as_float(bs);
      red[17] = __int_as_float(bj);
      red[18] = bm;
    }
    __syncthreads();
    const int   ptr_s = __float_as_int(red[16]);
    const int   ptr_j = __float_as_int(red[17]);
    const float m     = red[18];

    // G2: sum exp(logit - m) over active (removed columns contribute exact 0)
    if (tid < 256) {
      float e = (j8 < nact) ? expf(__fsub_rn(sc[j8], m)) : 0.f;
      #pragma unroll
      for (int off = 1; off < 64; off <<= 1) e += __shfl_xor(e, off);
      if ((tid & 63) == 0) red[20 + (tid >> 6)] = e;
    }
    __syncthreads();
    // H: outputs + swap-remove chosen column.
    // logp = (logit - m) - log(sum) : association matches jax.nn.log_softmax.
    if (tid == 0) {
      float tot = ((red[20] + red[21]) + red[22]) + red[23];
      float logp = __fsub_rn(__fsub_rn(sc[ptr_j], m), logf(tot));
#if TOURS_AS_INT
      ((int*)out)[b * SS + t] = ptr_s;
#else
      out[b * SS + t] = (float)ptr_s;
#endif
      out[BB * SS + b * SS + t] = logp;
      alist[ptr_j] = alist[nact - 1];
      nactS = nact - 1;
    }
    // no trailing barrier: next step's phase-A/D barriers order these LDS
    // writes before any cross-thread read (audited: sc/kv/red/alist/nactS all
    // re-read only after >=1 intervening __syncthreads).
  }
}

extern "C" void kernel_launch(void* const* d_in, const int* in_sizes, int n_in,
                              void* d_out, int out_size, void* d_ws, size_t ws_size,
                              hipStream_t stream) {
  (void)in_sizes; (void)n_in; (void)out_size; (void)ws_size;
  // setup_inputs order:
  // 0 static (unused), 1 static_embeddings, 2 dynamic, 3 Wdyn, 4 bdyn,
  // 5 Wdec, 6 bdec, 7 Wih, 8 Whh, 9 bih, 10 bhh, 11 Wa, 12 v_att
  const float* SE      = (const float*)d_in[1];
  const float* dynamic = (const float*)d_in[2];
  const float* Wdyn    = (const float*)d_in[3];
  const float* bdyn    = (const float*)d_in[4];
  const float* Wdec    = (const float*)d_in[5];
  const float* bdec    = (const float*)d_in[6];
  const float* Wih     = (const float*)d_in[7];
  const float* Whh     = (const float*)d_in[8];
  const float* bih     = (const float*)d_in[9];
  const float* bhh     = (const float*)d_in[10];
  const float* Wa      = (const float*)d_in[11];
  const float* v_att   = (const float*)d_in[12];
  float* out = (float*)d_out;
  float* ws  = (float*)d_ws;   // needs 163840 floats = 640 KiB

  transpose_weights<<<640, 256, 0, stream>>>(Wdec, Wih, Whh, Wa, ws);
  ptrnet_megakernel<<<BB, NT, 0, stream>>>(SE, dynamic, Wdyn, bdyn, Wa, v_att,
                                           bdec, bih, bhh, ws, out);
}

// Round 5
// 2773.404 us; speedup vs baseline: 1.0666x; 1.0666x over previous
//
#include <hip/hip_runtime.h>
#include <stdint.h>

// Problem constants (B,F,S,H) = (256, 2, 256, 128)
#define BB 256
#define SS 256
#define HH 128
#define NT 512
#define CHUNK 8
#define GLD 132   // G_T row stride in floats: 33 x 16B granules, 33 % 32 == 1
#define NEG_INF (-3.402823466e+38f)

#define JAX_PARTITIONABLE 1
#define TOURS_AS_INT 0

// NOTE (validated r4): accumulation ORDER in every dot product / reduce is
// load-bearing — the LSTM recurrence chaos-amplifies reorder noise over 256
// steps (absmax 0.0078 with current orders). All changes below are thread-
// MAPPING only; every arithmetic sequence is bit-identical to r4.

// ---------------- threefry-2x32 (exact JAX rotation/injection schedule) -----
__device__ __forceinline__ void tf2x32(unsigned int k0, unsigned int k1,
                                       unsigned int x0, unsigned int x1,
                                       unsigned int& o0, unsigned int& o1) {
  unsigned int k2 = k0 ^ k1 ^ 0x1BD11BDAu;
  x0 += k0; x1 += k1;
#define TFR(r) { x0 += x1; x1 = (x1 << (r)) | (x1 >> (32 - (r))); x1 ^= x0; }
  TFR(13) TFR(15) TFR(26) TFR(6)
  x0 += k1; x1 += k2 + 1u;
  TFR(17) TFR(29) TFR(16) TFR(24)
  x0 += k2; x1 += k0 + 2u;
  TFR(13) TFR(15) TFR(26) TFR(6)
  x0 += k0; x1 += k1 + 3u;
  TFR(17) TFR(29) TFR(16) TFR(24)
  x0 += k1; x1 += k2 + 4u;
  TFR(13) TFR(15) TFR(26) TFR(6)
  x0 += k2; x1 += k0 + 5u;
#undef TFR
  o0 = x0; o1 = x1;
}

__device__ __forceinline__ float gumbel_from_bits(unsigned int bits) {
  unsigned int fb = (bits >> 9) | 0x3f800000u;
  float f = __uint_as_float(fb) - 1.0f;   // [0,1)
  f = (f == 0.0f) ? 1.17549435e-38f : f;
  return -logf(-logf(f));
}

// ---------------- XLA EmitTanh (clamp +-9, Eigen rational), unfused ---------
__device__ __forceinline__ float xla_tanh(float x) {
  float ax = fabsf(x);
  float xc = fminf(fmaxf(x, -9.0f), 9.0f);
  float x2 = __fmul_rn(xc, xc);
  float p = -2.76076847742355e-16f;
  p = __fadd_rn(__fmul_rn(x2, p),  2.00018790482477e-13f);
  p = __fadd_rn(__fmul_rn(x2, p), -8.60467152213735e-11f);
  p = __fadd_rn(__fmul_rn(x2, p),  5.12229709037114e-08f);
  p = __fadd_rn(__fmul_rn(x2, p),  1.48572235717979e-05f);
  p = __fadd_rn(__fmul_rn(x2, p),  6.37261928875436e-04f);
  p = __fadd_rn(__fmul_rn(x2, p),  4.89352455891786e-03f);
  p = __fmul_rn(xc, p);
  float q = 1.19825839466702e-06f;
  q = __fadd_rn(__fmul_rn(x2, q), 1.18534705686654e-04f);
  q = __fadd_rn(__fmul_rn(x2, q), 2.26843463243900e-03f);
  q = __fadd_rn(__fmul_rn(x2, q), 4.89352518554385e-03f);
  float r = __fdiv_rn(p, q);
  return (ax < 0.0004f) ? x : r;
}

__device__ __forceinline__ float xla_sigmoid(float x) {
  return __fadd_rn(0.5f, __fmul_rn(0.5f, xla_tanh(__fmul_rn(0.5f, x))));
}

// ---------------- weight transposes into ws ---------------------------------
__global__ void transpose_weights(const float* __restrict__ Wdec,
                                  const float* __restrict__ Wih,
                                  const float* __restrict__ Whh,
                                  const float* __restrict__ Wa,
                                  float* __restrict__ ws) {
  int i = blockIdx.x * blockDim.x + threadIdx.x;
  if (i < 16384) {
    int k = i >> 7, j = i & 127;
    ws[i] = Wdec[j * 128 + k];
  } else if (i < 16384 + 65536) {
    int r = i - 16384; int k = r >> 9, g = r & 511;
    ws[16384 + r] = Wih[g * 128 + k];
  } else if (i < 16384 + 131072) {
    int r = i - 81920; int k = r >> 9, g = r & 511;
    ws[81920 + r] = Whh[g * 128 + k];
  } else if (i < 16384 + 131072 + 16384) {
    int r = i - 147456; int k = r >> 7, h = r & 127;
    ws[147456 + r] = Wa[h * 384 + 256 + k];
  }
}

// ---------------- persistent per-batch mega-kernel --------------------------
__global__ __launch_bounds__(NT, 2)
void ptrnet_megakernel(const float* __restrict__ SE,     // (B,H,S)
                       const float* __restrict__ dyn,    // (B,F,S)
                       const float* __restrict__ Wdyn,   // (H,F)
                       const float* __restrict__ bdyn,   // (H)
                       const float* __restrict__ Wa,     // (H,3H)
                       const float* __restrict__ v_att,  // (H)
                       const float* __restrict__ bdec_g, // (H)
                       const float* __restrict__ bih,    // (4H)
                       const float* __restrict__ bhh,    // (4H)
                       const float* __restrict__ ws,     // transposed weights
                       float* __restrict__ out)          // tours(B,S)|logps(B,S)
{
  const int b    = blockIdx.x;
  const int tid  = threadIdx.x;
  const int j8   = tid & 255;   // legacy mapping (precompute phase)
  const int half = tid >> 8;    // legacy mapping (precompute phase)
  const int jd   = tid & 127;   // output index, partitioned GEMVs
  const int pd   = tid >> 7;    // k-partition 0..3, partitioned GEMVs

  const float* WdecT = ws;            // [k][j]
  const float* WihT  = ws + 16384;    // [k][g]
  const float* WhhT  = ws + 81920;    // [k][g]
  const float* Wa3T  = ws + 147456;   // [k][h]

  __shared__ __align__(16) float G_T[SS * GLD];       // 132 KiB
  __shared__ __align__(16) float gxbuf[CHUNK][NT];    // 16 KiB
  __shared__ __align__(16) float xbuf[CHUNK + 1][HH]; // 4.5 KiB (row 0=carry)
  __shared__ __align__(16) float gate[NT];            // GEMV/reduce scratch
  __shared__ __align__(16) float hS[HH], cS[HH], w3h[HH], vS[HH], bdecS[HH];
  __shared__ float sc[SS], kv[SS];
  __shared__ float red[32];
  __shared__ unsigned char alist[SS];
  __shared__ int nactS;

  // ---- Precompute G_T[s][h] (identical to r4) ----
  {
    float* Msh  = &xbuf[0][0];
    float* c2   = &xbuf[2][0];
    float* SEst = &gxbuf[0][0];
    if (tid < 256) {
      int h = tid >> 1, f = tid & 1;
      float a = 0.f;
      for (int k = 0; k < HH; ++k)
        a = fmaf(Wa[h * 384 + 128 + k], Wdyn[k * 2 + f], a);
      Msh[tid] = a;
    } else if (tid < 384) {
      int h = tid - 256;
      float a = 0.f;
      for (int k = 0; k < HH; ++k)
        a = fmaf(Wa[h * 384 + 128 + k], bdyn[k], a);
      c2[h] = a;
    }
    __syncthreads();
    {
      float d0 = dyn[(size_t)(b * 2 + 0) * SS + j8];
      float d1 = dyn[(size_t)(b * 2 + 1) * SS + j8];
      const int h0 = half << 6;
      #pragma unroll 4
      for (int i4 = 0; i4 < 16; ++i4) {
        int h = h0 + i4 * 4;
        float4 g;
        g.x = c2[h + 0] + Msh[(h + 0) * 2] * d0 + Msh[(h + 0) * 2 + 1] * d1;
        g.y = c2[h + 1] + Msh[(h + 1) * 2] * d0 + Msh[(h + 1) * 2 + 1] * d1;
        g.z = c2[h + 2] + Msh[(h + 2) * 2] * d0 + Msh[(h + 2) * 2 + 1] * d1;
        g.w = c2[h + 3] + Msh[(h + 3) * 2] * d0 + Msh[(h + 3) * 2 + 1] * d1;
        *(float4*)&G_T[j8 * GLD + h] = g;
      }
    }
    __syncthreads();
    for (int kt = 0; kt < 16; ++kt) {
      #pragma unroll
      for (int r = 0; r < 4; ++r) {
        int idx = r * 512 + tid;
        int kk = idx >> 8, ssx = idx & 255;
        SEst[kk * 256 + ssx] = SE[(size_t)(b * HH + kt * 8 + kk) * SS + ssx];
      }
      __syncthreads();
      float se[8];
      #pragma unroll
      for (int j = 0; j < 8; ++j) se[j] = SEst[j * 256 + j8];
      const int h0 = half << 6;
      for (int i4 = 0; i4 < 16; ++i4) {
        int h = h0 + i4 * 4;
        float4 g = *(const float4*)&G_T[j8 * GLD + h];
        #pragma unroll
        for (int c = 0; c < 4; ++c) {
          const float* war = Wa + (h + c) * 384 + kt * 8;
          float a = 0.f;
          #pragma unroll
          for (int j = 0; j < 8; ++j) a = fmaf(war[j], se[j], a);
          ((float*)&g)[c] += a;
        }
        *(float4*)&G_T[j8 * GLD + h] = g;
      }
      __syncthreads();
    }
  }

  // ---- init rollout state ----
  if (tid < HH) {
    hS[tid] = 0.f; cS[tid] = 0.f;
    xbuf[0][tid] = SE[(size_t)(b * HH + tid) * SS];
    bdecS[tid] = bdec_g[tid];
    vS[tid]    = v_att[tid];
  }
  if (tid < 256) alist[tid] = (unsigned char)tid;
  if (tid == 0) nactS = 256;

  // ---- pin long-lived weight slices (same as r4: 192 floats) ----
  float whh_r[HH];
  #pragma unroll
  for (int k = 0; k < HH; ++k) whh_r[k] = WhhT[k * 512 + tid];
  float wdec_r[32];
  #pragma unroll
  for (int kk = 0; kk < 32; ++kk) wdec_r[kk] = WdecT[(pd * 32 + kk) * HH + jd];
  float wa3_r[32];
  #pragma unroll
  for (int kk = 0; kk < 32; ++kk) wa3_r[kk] = Wa3T[(pd * 32 + kk) * HH + jd];
  __syncthreads();

  // ---- 256 sequential decode steps ----
  for (int t = 0; t < SS; ++t) {
    const int i = t & (CHUNK - 1);

    if (i == 0) {
      // chunk prologue (identical to r4)
      for (int ii = 0; ii < CHUNK; ++ii) {
        float a = 0.f;
        #pragma unroll
        for (int kk = 0; kk < 32; ++kk)
          a = fmaf(xbuf[ii][pd * 32 + kk], wdec_r[kk], a);
        gate[pd * 128 + jd] = a;
        __syncthreads();
        if (tid < HH) {
          float sum = ((gate[tid] + gate[128 + tid]) + gate[256 + tid]) + gate[384 + tid];
          xbuf[ii + 1][tid] = __fadd_rn(sum, bdecS[tid]);
        }
        __syncthreads();
      }
      if (tid < HH) xbuf[0][tid] = xbuf[CHUNK][tid];
      float bihhh = bih[tid] + bhh[tid];
      #pragma unroll
      for (int pass = 0; pass < 2; ++pass) {
        const float* xA = &xbuf[pass * 4 + 1][0];
        const float* xB = &xbuf[pass * 4 + 2][0];
        const float* xC = &xbuf[pass * 4 + 3][0];
        const float* xD = &xbuf[pass * 4 + 4][0];
        float a0 = bihhh, a1 = bihhh, a2 = bihhh, a3 = bihhh;
        #pragma unroll 8
        for (int k4 = 0; k4 < 32; ++k4) {
          float w0 = WihT[(k4 * 4 + 0) * 512 + tid];
          float w1 = WihT[(k4 * 4 + 1) * 512 + tid];
          float w2 = WihT[(k4 * 4 + 2) * 512 + tid];
          float w3 = WihT[(k4 * 4 + 3) * 512 + tid];
          float4 va = *(const float4*)&xA[k4 * 4];
          float4 vb = *(const float4*)&xB[k4 * 4];
          float4 vc = *(const float4*)&xC[k4 * 4];
          float4 vd = *(const float4*)&xD[k4 * 4];
          a0 = fmaf(va.x, w0, a0); a0 = fmaf(va.y, w1, a0);
          a0 = fmaf(va.z, w2, a0); a0 = fmaf(va.w, w3, a0);
          a1 = fmaf(vb.x, w0, a1); a1 = fmaf(vb.y, w1, a1);
          a1 = fmaf(vb.z, w2, a1); a1 = fmaf(vb.w, w3, a1);
          a2 = fmaf(vc.x, w0, a2); a2 = fmaf(vc.y, w1, a2);
          a2 = fmaf(vc.z, w2, a2); a2 = fmaf(vc.w, w3, a2);
          a3 = fmaf(vd.x, w0, a3); a3 = fmaf(vd.y, w1, a3);
          a3 = fmaf(vd.z, w2, a3); a3 = fmaf(vd.w, w3, a3);
        }
        gxbuf[pass * 4 + 0][tid] = a0;
        gxbuf[pass * 4 + 1][tid] = a1;
        gxbuf[pass * 4 + 2][tid] = a2;
        gxbuf[pass * 4 + 3][tid] = a3;
      }
      __syncthreads();
    }

    // A: gates = gx + h @ Whh^T (k-ascending, identical order)
    {
      float g = gxbuf[i][tid];
      #pragma unroll
      for (int k4 = 0; k4 < HH / 4; ++k4) {
        float4 hv = *(const float4*)&hS[k4 * 4];
        g = fmaf(hv.x, whh_r[k4 * 4 + 0], g);
        g = fmaf(hv.y, whh_r[k4 * 4 + 1], g);
        g = fmaf(hv.z, whh_r[k4 * 4 + 2], g);
        g = fmaf(hv.w, whh_r[k4 * 4 + 3], g);
      }
      gate[tid] = g;
    }
    __syncthreads();
    // C: LSTM cell — remapped to lanes 0-31 of waves 0-3 (all 4 SIMDs);
    // per-h arithmetic identical to r4.
    if (tid < 256 && (tid & 63) < 32) {
      int h = ((tid >> 6) << 5) + (tid & 31);
      float gi = gate[h], gf = gate[128 + h];
      float gg = gate[256 + h], go = gate[384 + h];
      float c_new = __fadd_rn(__fmul_rn(xla_sigmoid(gf), cS[h]),
                              __fmul_rn(xla_sigmoid(gi), xla_tanh(gg)));
      float h_new = __fmul_rn(xla_sigmoid(go), xla_tanh(c_new));
      cS[h] = c_new; hS[h] = h_new;
    }
    __syncthreads();

    if (t == 0) {
      if (tid == 0) {
#if TOURS_AS_INT
        ((int*)out)[b * SS + 0] = 0;
#else
        out[b * SS + 0] = 0.0f;
#endif
        out[BB * SS + b * SS + 0] = 0.0f;
        alist[0] = alist[255];
        nactS = 255;
      }
      continue;
    }

    // D: w3h = Wa3 @ h (partitioned 4x32; identical order)
    {
      float a = 0.f;
      #pragma unroll
      for (int kk = 0; kk < 32; ++kk)
        a = fmaf(hS[pd * 32 + kk], wa3_r[kk], a);
      gate[pd * 128 + jd] = a;
    }
    __syncthreads();
    if (tid < HH)
      w3h[tid] = ((gate[tid] + gate[128 + tid]) + gate[256 + tid]) + gate[384 + tid];
    __syncthreads();

    const int nact = nactS;

    // E: partial scores — REMAPPED: halfe=tid&1, j8e=tid>>1 so active
    // threads are contiguous [0, 2*nact) -> waves spread over all SIMDs.
    // Per-(s,half) arithmetic identical to r4.
    {
      const int j8e   = tid >> 1;
      const int halfe = tid & 1;
      if (j8e < nact) {
        const int s = alist[j8e];
        const float* grow = &G_T[s * GLD];
        float acc = 0.f;
        const int h0 = halfe << 6;
        #pragma unroll 4
        for (int i4 = 0; i4 < 16; ++i4) {
          int h = h0 + i4 * 4;
          float4 gv = *(const float4*)&grow[h];
          float4 wv = *(const float4*)&w3h[h];
          float4 vv = *(const float4*)&vS[h];
          float z0 = __fadd_rn(gv.x, wv.x);
          float z1 = __fadd_rn(gv.y, wv.y);
          float z2 = __fadd_rn(gv.z, wv.z);
          float z3 = __fadd_rn(gv.w, wv.w);
          acc = fmaf(vv.x, xla_tanh(z0), acc);
          acc = fmaf(vv.y, xla_tanh(z1), acc);
          acc = fmaf(vv.z, xla_tanh(z2), acc);
          acc = fmaf(vv.w, xla_tanh(z3), acc);
        }
        if (halfe == 0) sc[j8e] = acc; else kv[j8e] = acc;
      }
    }
    __syncthreads();

    // F+G1: logits (kept in register) + gumbel keys + per-wave reduce
    float flogit = NEG_INF;   // valid where tid<256 && tid<nact
    if (tid < 256) {
      float val, mx; int sidx, jpos;
      if (tid < nact) {
        const int s = alist[tid];
        flogit = __fadd_rn(sc[tid], kv[tid]);   // same order as r4: sc+kv
        unsigned int fk0, fk1, o0, o1, bits;
        tf2x32(0u, 42u, 0u, (unsigned int)t, fk0, fk1);
#if JAX_PARTITIONABLE
        tf2x32(fk0, fk1, 0u, (unsigned int)(b * 256 + s), o0, o1);
        bits = o0 ^ o1;
#else
        int jj = b * 256 + s;
        if (jj < 32768) { tf2x32(fk0, fk1, (unsigned)jj, (unsigned)(jj + 32768), o0, o1); bits = o0; }
        else            { tf2x32(fk0, fk1, (unsigned)(jj - 32768), (unsigned)jj, o0, o1); bits = o1; }
#endif
        float gum = gumbel_from_bits(bits);
        val = __fadd_rn(flogit, gum);
        mx = flogit; sidx = s; jpos = tid;
      } else {
        val = -INFINITY; mx = -INFINITY; sidx = 0x7FFFFFFF; jpos = 0;
      }
      #pragma unroll
      for (int off = 1; off < 64; off <<= 1) {
        float ov = __shfl_xor(val, off);
        int   oi = __shfl_xor(sidx, off);
        int   oj = __shfl_xor(jpos, off);
        float om = __shfl_xor(mx, off);
        if (ov > val || (ov == val && oi < sidx)) { val = ov; sidx = oi; jpos = oj; }
        mx = fmaxf(mx, om);
      }
      if ((tid & 63) == 0) {
        int w = tid >> 6;
        red[w * 4 + 0] = val;
        red[w * 4 + 1] = __int_as_float(sidx);
        red[w * 4 + 2] = __int_as_float(jpos);
        red[w * 4 + 3] = mx;
      }
    }
    __syncthreads();

    // G1-finalize locally (identical compare/sum order as r4's tid0 code),
    // then G2 exp-sum from the register logit.
    if (tid < 256) {
      float bv = red[0]; int bs = __float_as_int(red[1]);
      int bj = __float_as_int(red[2]); float bm = red[3];
      #pragma unroll
      for (int w = 1; w < 4; ++w) {
        float ov = red[w * 4], om = red[w * 4 + 3];
        int os = __float_as_int(red[w * 4 + 1]);
        int oj = __float_as_int(red[w * 4 + 2]);
        if (ov > bv || (ov == bv && os < bs)) { bv = ov; bs = os; bj = oj; }
        bm = fmaxf(bm, om);
      }
      float e = (tid < nact) ? expf(__fsub_rn(flogit, bm)) : 0.f;
      #pragma unroll
      for (int off = 1; off < 64; off <<= 1) e += __shfl_xor(e, off);
      if ((tid & 63) == 0) red[20 + (tid >> 6)] = e;
      // stash winner info for post-barrier use (registers, all threads agree)
      if (tid == 0) { red[16] = __int_as_float(bs); red[17] = __int_as_float(bj); red[18] = bm; }
    }
    __syncthreads();

    // H: winner thread writes outputs + swap-remove (no extra barrier)
    {
      const int bj = __float_as_int(red[17]);
      if (tid == bj) {  // exactly one thread (bj < nact <= 256)
        const int   bs = __float_as_int(red[16]);
        const float bm = red[18];
        float tot = ((red[20] + red[21]) + red[22]) + red[23];
        float logp = __fsub_rn(__fsub_rn(flogit, bm), logf(tot));
#if TOURS_AS_INT
        ((int*)out)[b * SS + t] = bs;
#else
        out[b * SS + t] = (float)bs;
#endif
        out[BB * SS + b * SS + t] = logp;
        alist[bj] = alist[nact - 1];
        nactS = nact - 1;
      }
    }
    // next reads of alist/nactS/red occur >=1 barrier later (A/C/D barriers)
  }
}

extern "C" void kernel_launch(void* const* d_in, const int* in_sizes, int n_in,
                              void* d_out, int out_size, void* d_ws, size_t ws_size,
                              hipStream_t stream) {
  (void)in_sizes; (void)n_in; (void)out_size; (void)ws_size;
  const float* SE      = (const float*)d_in[1];
  const float* dynamic = (const float*)d_in[2];
  const float* Wdyn    = (const float*)d_in[3];
  const float* bdyn    = (const float*)d_in[4];
  const float* Wdec    = (const float*)d_in[5];
  const float* bdec    = (const float*)d_in[6];
  const float* Wih     = (const float*)d_in[7];
  const float* Whh     = (const float*)d_in[8];
  const float* bih     = (const float*)d_in[9];
  const float* bhh     = (const float*)d_in[10];
  const float* Wa      = (const float*)d_in[11];
  const float* v_att   = (const float*)d_in[12];
  float* out = (float*)d_out;
  float* ws  = (float*)d_ws;   // 163840 floats = 640 KiB

  transpose_weights<<<640, 256, 0, stream>>>(Wdec, Wih, Whh, Wa, ws);
  ptrnet_megakernel<<<BB, NT, 0, stream>>>(SE, dynamic, Wdyn, bdyn, Wa, v_att,
                                           bdec, bih, bhh, ws, out);
}